// Round 4
// baseline (337.987 us; speedup 1.0000x reference)
//
#include <hip/hip_runtime.h>
#include <cstddef>

// Problem constants (fixed by the reference)
constexpr int Bn = 2048;   // batch
constexpr int In = 4096;   // rated items
constexpr int Dn = 512;    // embedding dim

typedef _Float16 f16;
typedef _Float16 f16x8 __attribute__((ext_vector_type(8)));
typedef _Float16 f16x4 __attribute__((ext_vector_type(4)));
typedef float    f32x4 __attribute__((ext_vector_type(4)));

// ---------------------------------------------------------------------------
// rs[i] = rated_items[i,:] . att_w[D:2D]  (per-item attention logit).
// cs[b] and att_b are row-constant -> cancel in the row softmax.
// ---------------------------------------------------------------------------
__global__ __launch_bounds__(256) void k_rs(const float* __restrict__ rated,
                                            const float* __restrict__ att_w,
                                            float* __restrict__ rs) {
  const int wid  = threadIdx.x >> 6;
  const int lane = threadIdx.x & 63;
  const int i = blockIdx.x * 4 + wid;
  const float* row = rated + (size_t)i * Dn;
  const float* wr  = att_w + Dn;
  float s = 0.f;
  #pragma unroll
  for (int d = 0; d < Dn / 64; ++d)
    s = fmaf(row[lane + d * 64], wr[lane + d * 64], s);
  #pragma unroll
  for (int off = 32; off > 0; off >>= 1) s += __shfl_down(s, off);
  if (lane == 0) rs[i] = s;
}

// ---------------------------------------------------------------------------
// user_feat[b,:] = (softmax-masked att * user_matrix) @ rated_items
// One block per row. Exploits ~5% sparsity of user_matrix. fp32 math,
// fp16 output (feeds the fp16 MFMA GEMM chain).
// ---------------------------------------------------------------------------
__global__ __launch_bounds__(256) void k_userfeat(const float* __restrict__ um,
                                                  const float* __restrict__ rs,
                                                  const float* __restrict__ rated,
                                                  f16* __restrict__ uf) {
  __shared__ unsigned short s_idx[In];
  __shared__ float s_coef[In];
  __shared__ float s_red[8];
  __shared__ int s_cnt;
  const int tid = threadIdx.x;
  const int b = blockIdx.x;
  if (tid == 0) s_cnt = 0;
  __syncthreads();

  // pass 1: compact nonzeros, local max of rs over support
  const float* umrow = um + (size_t)b * In;
  float lmax = -INFINITY;
  #pragma unroll
  for (int it = 0; it < In / 256; ++it) {
    const int i = tid + it * 256;
    const float u = umrow[i];
    if (u != 0.0f) {
      const int p = atomicAdd(&s_cnt, 1);
      s_idx[p] = (unsigned short)i;
      s_coef[p] = u;                 // temporarily holds user_matrix value
      lmax = fmaxf(lmax, rs[i]);
    }
  }
  __syncthreads();
  const int n = s_cnt;

  // block max reduce
  #pragma unroll
  for (int off = 32; off > 0; off >>= 1) lmax = fmaxf(lmax, __shfl_down(lmax, off));
  if ((tid & 63) == 0) s_red[tid >> 6] = lmax;
  __syncthreads();
  const float m = fmaxf(fmaxf(s_red[0], s_red[1]), fmaxf(s_red[2], s_red[3]));
  __syncthreads();

  // pass 2: s_coef[j] := exp(rs[i]-m) * um[i]; accumulate sum of exps
  float lsum = 0.f;
  for (int j = tid; j < n; j += 256) {
    const float t = __expf(rs[s_idx[j]] - m);
    lsum += t;
    s_coef[j] = t * s_coef[j];
  }
  __syncthreads();
  #pragma unroll
  for (int off = 32; off > 0; off >>= 1) lsum += __shfl_down(lsum, off);
  if ((tid & 63) == 0) s_red[tid >> 6] = lsum;
  __syncthreads();
  const float S = s_red[0] + s_red[1] + s_red[2] + s_red[3];
  const float inv = (n > 0 && S > 0.f) ? 1.0f / S : 0.0f;

  // pass 3: d-parallel accumulation over the support
  float a0 = 0.f, a1 = 0.f;
  for (int j = 0; j < n; ++j) {
    const float c = s_coef[j];
    const float* rrow = rated + (size_t)s_idx[j] * Dn;
    a0 = fmaf(c, rrow[tid], a0);
    a1 = fmaf(c, rrow[tid + 256], a1);
  }
  uf[(size_t)b * Dn + tid]       = (f16)(a0 * inv);
  uf[(size_t)b * Dn + tid + 256] = (f16)(a1 * inv);
}

// ---------------------------------------------------------------------------
// Weight prep: src[K][N] fp32 -> dst[N][K] fp16 (transpose), 32x32 LDS tiles.
// Grid: (N/32, K/32), block 256 (32x8).
// ---------------------------------------------------------------------------
__global__ __launch_bounds__(256) void k_transpose_f2h(const float* __restrict__ src,
                                                       f16* __restrict__ dst,
                                                       int K, int N) {
  __shared__ float tile[32][33];
  const int tx = threadIdx.x & 31;
  const int ty = threadIdx.x >> 5;      // 0..7
  const int n0 = blockIdx.x * 32;
  const int k0 = blockIdx.y * 32;
  #pragma unroll
  for (int i = 0; i < 4; ++i)
    tile[ty + i * 8][tx] = src[(size_t)(k0 + ty + i * 8) * N + n0 + tx];
  __syncthreads();
  #pragma unroll
  for (int i = 0; i < 4; ++i)
    dst[(size_t)(n0 + ty + i * 8) * K + k0 + tx] = (f16)tile[tx][ty + i * 8];
}

// Plain fp32 -> fp16 cast (for candidate_items). n multiple of 1024.
__global__ __launch_bounds__(256) void k_cast_f2h(const float* __restrict__ src,
                                                  f16* __restrict__ dst, int n) {
  const int i = (blockIdx.x * 256 + threadIdx.x) * 4;
  if (i < n) {
    const float4 v = *reinterpret_cast<const float4*>(src + i);
    f16x4 h; h.x = (f16)v.x; h.y = (f16)v.y; h.z = (f16)v.z; h.w = (f16)v.w;
    *reinterpret_cast<f16x4*>(dst + i) = h;
  }
}

// ---------------------------------------------------------------------------
// Fused C = act(A @ W + bias), fp16 in / fp32 acc / fp16 out, MFMA.
//   A : MxK row-major fp16 (lda = K)
//   Wt: NxK row-major fp16 (i.e. W transposed; contiguous-K columns)
//   C : MxN fp16, leading dim ldc (allows strided write into concat buffer)
// Tile: 64x64, 256 threads = 4 waves (2x2), each wave 32x32 = 2x2 MFMA frags
// of v_mfma_f32_16x16x32_f16. K-step 32, single-buffered LDS, 2 barriers.
// Fragment maps (HW-verified, m89 family):
//   A: row = lane&15, k = contiguous 8 per lane-group (bijection-safe)
//   B: col = lane&15, k = contiguous 8 per lane-group
//   C/D: col = lane&15, row = (lane>>4)*4 + reg
// ---------------------------------------------------------------------------
template <bool RELU>
__global__ __launch_bounds__(256) void k_hgemm(const f16* __restrict__ A,
                                               const f16* __restrict__ Wt,
                                               const float* __restrict__ bias,
                                               f16* __restrict__ C, int ldc,
                                               int N, int K) {
  __shared__ __align__(16) f16 As[64][40];   // 32 + 8 pad (rows stay 16B-aligned)
  __shared__ __align__(16) f16 Bs[64][40];

  const int tid  = threadIdx.x;
  const int lane = tid & 63;
  const int wave = tid >> 6;            // 0..3
  const int wr   = (wave >> 1) * 32;    // wave row offset in tile
  const int wc   = (wave & 1) * 32;     // wave col offset in tile
  const int lrow = lane & 15;
  const int koff = (lane >> 4) * 8;     // 0,8,16,24

  const int bm = blockIdx.y * 64;
  const int bn = blockIdx.x * 64;

  // staging assignment: thread -> (row r, 8-half chunk cof)
  const int r   = tid >> 2;             // 0..63
  const int cof = (tid & 3) * 8;        // 0,8,16,24

  const f16* pa = A  + (size_t)(bm + r) * K + cof;
  const f16* pb = Wt + (size_t)(bn + r) * K + cof;

  f32x4 acc[2][2] = {};

  for (int k0 = 0; k0 < K; k0 += 32, pa += 32, pb += 32) {
    *reinterpret_cast<f16x8*>(&As[r][cof]) = *reinterpret_cast<const f16x8*>(pa);
    *reinterpret_cast<f16x8*>(&Bs[r][cof]) = *reinterpret_cast<const f16x8*>(pb);
    __syncthreads();

    const f16x8 a0 = *reinterpret_cast<const f16x8*>(&As[wr + lrow][koff]);
    const f16x8 a1 = *reinterpret_cast<const f16x8*>(&As[wr + 16 + lrow][koff]);
    const f16x8 b0 = *reinterpret_cast<const f16x8*>(&Bs[wc + lrow][koff]);
    const f16x8 b1 = *reinterpret_cast<const f16x8*>(&Bs[wc + 16 + lrow][koff]);

    acc[0][0] = __builtin_amdgcn_mfma_f32_16x16x32_f16(a0, b0, acc[0][0], 0, 0, 0);
    acc[0][1] = __builtin_amdgcn_mfma_f32_16x16x32_f16(a0, b1, acc[0][1], 0, 0, 0);
    acc[1][0] = __builtin_amdgcn_mfma_f32_16x16x32_f16(a1, b0, acc[1][0], 0, 0, 0);
    acc[1][1] = __builtin_amdgcn_mfma_f32_16x16x32_f16(a1, b1, acc[1][1], 0, 0, 0);
    __syncthreads();
  }

  // epilogue: bias + ReLU + fp16 store
  const int orow = (lane >> 4) * 4;
  #pragma unroll
  for (int m = 0; m < 2; ++m)
    #pragma unroll
    for (int nn = 0; nn < 2; ++nn) {
      const int col = bn + wc + nn * 16 + lrow;
      const float bv = bias[col];
      #pragma unroll
      for (int rr = 0; rr < 4; ++rr) {
        const int row = bm + wr + m * 16 + orow + rr;
        float v = acc[m][nn][rr] + bv;
        if (RELU) v = fmaxf(v, 0.f);
        C[(size_t)row * ldc + col] = (f16)v;
      }
    }
}

// ---------------------------------------------------------------------------
// out[b] = h3[b,:256] . mw4 + mb4   (one wave per row; h3 is fp16)
// ---------------------------------------------------------------------------
__global__ __launch_bounds__(256) void k_final(const f16* __restrict__ h3,
                                               const float* __restrict__ mw4,
                                               const float* __restrict__ mb4,
                                               float* __restrict__ out) {
  const int wid = threadIdx.x >> 6;
  const int lane = threadIdx.x & 63;
  const int row = blockIdx.x * 4 + wid;
  const f16* hr = h3 + (size_t)row * 256;
  float s = 0.f;
  #pragma unroll
  for (int d = 0; d < 4; ++d)
    s = fmaf((float)hr[lane + d * 64], mw4[lane + d * 64], s);
  #pragma unroll
  for (int off = 32; off > 0; off >>= 1) s += __shfl_down(s, off);
  if (lane == 0) out[row] = s + mb4[0];
}

// ---------------------------------------------------------------------------
extern "C" void kernel_launch(void* const* d_in, const int* in_sizes, int n_in,
                              void* d_out, int out_size, void* d_ws, size_t ws_size,
                              hipStream_t stream) {
  const float* cand  = (const float*)d_in[0];   // (2048, 512)
  const float* rated = (const float*)d_in[1];   // (4096, 512)
  const float* um    = (const float*)d_in[2];   // (2048, 4096)
  const float* att_w = (const float*)d_in[3];   // (1024, 1)
  // d_in[4] = att_b (cancels in softmax)
  const float* iw1 = (const float*)d_in[5];     // (512, 1024)
  const float* ib1 = (const float*)d_in[6];
  const float* iw2 = (const float*)d_in[7];     // (1024, 512)
  const float* ib2 = (const float*)d_in[8];
  const float* uw1 = (const float*)d_in[9];     // (512, 2048)
  const float* ub1 = (const float*)d_in[10];
  const float* uw2 = (const float*)d_in[11];    // (2048, 1024)
  const float* ub2 = (const float*)d_in[12];
  const float* mw1 = (const float*)d_in[13];    // (1536, 1024)
  const float* mb1 = (const float*)d_in[14];
  const float* mw2 = (const float*)d_in[15];    // (1024, 512)
  const float* mb2 = (const float*)d_in[16];
  const float* mw3 = (const float*)d_in[17];    // (512, 256)
  const float* mb3 = (const float*)d_in[18];
  const float* mw4 = (const float*)d_in[19];    // (256, 1)
  const float* mb4 = (const float*)d_in[20];
  float* out = (float*)d_out;                   // (2048, 1)

  // ---- workspace layout (fp16 units unless noted); total ~31.7 MB ----
  f16*   hws = (f16*)d_ws;
  float* rs  = (float*)d_ws;            // 4096 fp32 = 8192 half-slots
  size_t off = 8192;
  auto take = [&](size_t n) { f16* p = hws + off; off += n; return p; };
  f16* t_iw1 = take(512 * 1024);
  f16* t_iw2 = take(1024 * 512);
  f16* t_uw1 = take(512 * 2048);
  f16* t_uw2 = take(2048 * 1024);
  f16* t_mw1 = take(1536 * 1024);
  f16* t_mw2 = take(1024 * 512);
  f16* t_mw3 = take(512 * 256);
  f16* cand_h = take(2048 * 512);
  f16* uf_h   = take(2048 * 512);
  f16* Xc     = take(2048 * 1536);      // concat [item_emb | user_emb]
  f16* big    = take(2048 * 2048);      // time-shared: h_i1 / h_u1 / h_m1
  f16* h_i1 = big;                      // 2048x1024
  f16* h_u1 = big;                      // 2048x2048 (h_i1 dead)
  f16* h_m1 = big;                      // 2048x1024 (h_u1 dead)
  f16* h_m2 = uf_h;                     // 2048x512  (uf dead after G3)
  f16* h_m3 = cand_h;                   // 2048x256  (cand_h dead after G1)

  dim3 blk(256);

  // 0. weight prep: fp32 [K][N] -> fp16 [N][K]; candidate cast
  k_transpose_f2h<<<dim3(1024/32,  512/32), blk, 0, stream>>>(iw1, t_iw1,  512, 1024);
  k_transpose_f2h<<<dim3( 512/32, 1024/32), blk, 0, stream>>>(iw2, t_iw2, 1024,  512);
  k_transpose_f2h<<<dim3(2048/32,  512/32), blk, 0, stream>>>(uw1, t_uw1,  512, 2048);
  k_transpose_f2h<<<dim3(1024/32, 2048/32), blk, 0, stream>>>(uw2, t_uw2, 2048, 1024);
  k_transpose_f2h<<<dim3(1024/32, 1536/32), blk, 0, stream>>>(mw1, t_mw1, 1536, 1024);
  k_transpose_f2h<<<dim3( 512/32, 1024/32), blk, 0, stream>>>(mw2, t_mw2, 1024,  512);
  k_transpose_f2h<<<dim3( 256/32,  512/32), blk, 0, stream>>>(mw3, t_mw3,  512,  256);
  k_cast_f2h<<<dim3(Bn * Dn / 1024), blk, 0, stream>>>(cand, cand_h, Bn * Dn);

  // 1. attention logits per item
  k_rs<<<dim3(In / 4), blk, 0, stream>>>(rated, att_w, rs);

  // 2. sparse softmax-weighted user features (fp16 out)
  k_userfeat<<<dim3(Bn), blk, 0, stream>>>(um, rs, rated, uf_h);

  // 3. item MLP
  k_hgemm<true><<<dim3(1024/64, Bn/64), blk, 0, stream>>>(cand_h, t_iw1, ib1, h_i1, 1024, 1024, 512);
  k_hgemm<true><<<dim3( 512/64, Bn/64), blk, 0, stream>>>(h_i1,   t_iw2, ib2, Xc,   1536,  512, 1024);

  // 4. user MLP (writes second half of concat buffer)
  k_hgemm<true><<<dim3(2048/64, Bn/64), blk, 0, stream>>>(uf_h, t_uw1, ub1, h_u1,     2048, 2048, 512);
  k_hgemm<true><<<dim3(1024/64, Bn/64), blk, 0, stream>>>(h_u1, t_uw2, ub2, Xc + 512, 1536, 1024, 2048);

  // 5. merge MLP
  k_hgemm<true><<<dim3(1024/64, Bn/64), blk, 0, stream>>>(Xc,   t_mw1, mb1, h_m1, 1024, 1024, 1536);
  k_hgemm<true><<<dim3( 512/64, Bn/64), blk, 0, stream>>>(h_m1, t_mw2, mb2, h_m2,  512,  512, 1024);
  k_hgemm<true><<<dim3( 256/64, Bn/64), blk, 0, stream>>>(h_m2, t_mw3, mb3, h_m3,  256,  256, 512);

  // 6. final projection (fp32 out)
  k_final<<<dim3(Bn / 4), blk, 0, stream>>>(h_m3, mw4, mb4, out);
}

// Round 7
// 320.492 us; speedup vs baseline: 1.0546x; 1.0546x over previous
//
#include <hip/hip_runtime.h>
#include <cstddef>

// Problem constants (fixed by the reference)
constexpr int Bn = 2048;   // batch
constexpr int In = 4096;   // rated items
constexpr int Dn = 512;    // embedding dim

typedef _Float16 f16;
typedef _Float16 f16x8 __attribute__((ext_vector_type(8)));
typedef float    f32x4 __attribute__((ext_vector_type(4)));

// ---------------------------------------------------------------------------
// rs[i] = rated_items[i,:] . att_w[D:2D]  (per-item attention logit).
// cs[b] and att_b are row-constant -> cancel in the row softmax.
// ---------------------------------------------------------------------------
__global__ __launch_bounds__(256) void k_rs(const float* __restrict__ rated,
                                            const float* __restrict__ att_w,
                                            float* __restrict__ rs) {
  const int wid  = threadIdx.x >> 6;
  const int lane = threadIdx.x & 63;
  const int i = blockIdx.x * 4 + wid;
  const float* row = rated + (size_t)i * Dn;
  const float* wr  = att_w + Dn;
  float s = 0.f;
  #pragma unroll
  for (int d = 0; d < Dn / 64; ++d)
    s = fmaf(row[lane + d * 64], wr[lane + d * 64], s);
  #pragma unroll
  for (int off = 32; off > 0; off >>= 1) s += __shfl_down(s, off);
  if (lane == 0) rs[i] = s;
}

// ---------------------------------------------------------------------------
// Dense fp16 attention-weight row:
//   w[b][i] = um!=0 ? exp(rs[i]-m_b)*um[b][i] / S_b : 0,   S_b = SUM exp(rs-m)
// (S is the softmax denominator: sum of exp over support, NOT um-weighted —
//  this was the round-6 bug.)  Rows with empty support -> all zeros.
// ---------------------------------------------------------------------------
__global__ __launch_bounds__(256) void k_att(const float* __restrict__ um,
                                             const float* __restrict__ rs,
                                             f16* __restrict__ att) {
  __shared__ float t[In];      // rs-or--inf, then unnormalized weight exp*um
  __shared__ float red[4];
  const int tid = threadIdx.x;
  const int b = blockIdx.x;
  const float* umrow = um + (size_t)b * In;

  float ua[16];
  float lmax = -INFINITY;
  #pragma unroll
  for (int it = 0; it < 4; ++it) {
    const int i = (it * 256 + tid) * 4;
    const float4 v = *reinterpret_cast<const float4*>(umrow + i);
    ua[it * 4 + 0] = v.x; ua[it * 4 + 1] = v.y;
    ua[it * 4 + 2] = v.z; ua[it * 4 + 3] = v.w;
    #pragma unroll
    for (int j = 0; j < 4; ++j) {
      if (ua[it * 4 + j] != 0.f) {
        const float r = rs[i + j];
        t[i + j] = r;
        lmax = fmaxf(lmax, r);
      } else {
        t[i + j] = -INFINITY;
      }
    }
  }
  #pragma unroll
  for (int off = 32; off > 0; off >>= 1) lmax = fmaxf(lmax, __shfl_down(lmax, off));
  if ((tid & 63) == 0) red[tid >> 6] = lmax;
  __syncthreads();
  const float m = fmaxf(fmaxf(red[0], red[1]), fmaxf(red[2], red[3]));
  __syncthreads();   // protect red[] before it is rewritten below

  float lsum = 0.f;
  #pragma unroll
  for (int it = 0; it < 4; ++it) {
    const int i = (it * 256 + tid) * 4;
    #pragma unroll
    for (int j = 0; j < 4; ++j) {
      float v = 0.f;
      if (ua[it * 4 + j] != 0.f) {
        const float e = __expf(t[i + j] - m);
        lsum += e;                    // softmax denominator: plain exp sum
        v = e * ua[it * 4 + j];       // numerator weight: exp * um
      }
      t[i + j] = v;   // own indices only; no race
    }
  }
  #pragma unroll
  for (int off = 32; off > 0; off >>= 1) lsum += __shfl_down(lsum, off);
  if ((tid & 63) == 0) red[tid >> 6] = lsum;
  __syncthreads();   // red visible AND all t[] writes visible
  const float S = red[0] + red[1] + red[2] + red[3];
  const float inv = (S > 0.f) ? 1.0f / S : 0.0f;

  f16* arow = att + (size_t)b * In;
  #pragma unroll
  for (int it = 0; it < 2; ++it) {
    const int i = (it * 256 + tid) * 8;
    f16x8 h;
    #pragma unroll
    for (int j = 0; j < 8; ++j) h[j] = (f16)(t[i + j] * inv);
    *reinterpret_cast<f16x8*>(arow + i) = h;
  }
}

// ---------------------------------------------------------------------------
// Weight prep: src[K][N] fp32 -> dst[N][K] fp16 (transpose), 32x32 LDS tiles.
// ---------------------------------------------------------------------------
__global__ __launch_bounds__(256) void k_transpose_f2h(const float* __restrict__ src,
                                                       f16* __restrict__ dst,
                                                       int K, int N) {
  __shared__ float tile[32][33];
  const int tx = threadIdx.x & 31;
  const int ty = threadIdx.x >> 5;      // 0..7
  const int n0 = blockIdx.x * 32;
  const int k0 = blockIdx.y * 32;
  #pragma unroll
  for (int i = 0; i < 4; ++i)
    tile[ty + i * 8][tx] = src[(size_t)(k0 + ty + i * 8) * N + n0 + tx];
  __syncthreads();
  #pragma unroll
  for (int i = 0; i < 4; ++i)
    dst[(size_t)(n0 + ty + i * 8) * K + k0 + tx] = (f16)tile[tx][ty + i * 8];
}

// Plain fp32 -> fp16 cast (for candidate_items). n multiple of 1024.
__global__ __launch_bounds__(256) void k_cast_f2h(const float* __restrict__ src,
                                                  f16* __restrict__ dst, int n) {
  const int i = (blockIdx.x * 256 + threadIdx.x) * 4;
  if (i < n) {
    const float4 v = *reinterpret_cast<const float4*>(src + i);
    f16 h0 = (f16)v.x, h1 = (f16)v.y, h2 = (f16)v.z, h3 = (f16)v.w;
    f16* p = dst + i;
    p[0] = h0; p[1] = h1; p[2] = h2; p[3] = h3;
  }
}

// ---------------------------------------------------------------------------
// Fused C = act(A @ W + bias), fp16 in / fp32 acc / fp16 out, MFMA.
//   A : MxK row-major fp16, Wt: NxK row-major fp16 (W transposed),
//   C : MxN fp16 with leading dim ldc (strided write into concat buffer).
// Tile 128Mx64N, BK=64, 256 threads = 4 waves (2x2); wave computes 64x32
// = 4x2 frags of v_mfma_f32_16x16x32_f16. Register prefetch of next K-tile
// issued before the MFMA cluster (T14-lite). Fragment maps identical to the
// HW-verified round-4 kernel (passed, absmax 3e-5).
// ---------------------------------------------------------------------------
template <bool RELU, bool BIAS>
__global__ __launch_bounds__(256) void k_hgemm(const f16* __restrict__ A,
                                               const f16* __restrict__ Wt,
                                               const float* __restrict__ bias,
                                               f16* __restrict__ C, int ldc,
                                               int N, int K) {
  __shared__ __align__(16) f16 As[128][72];   // 64 + 8 pad (rows 144B, 16B-aligned)
  __shared__ __align__(16) f16 Bs[64][72];

  const int tid  = threadIdx.x;
  const int lane = tid & 63;
  const int wave = tid >> 6;            // 0..3
  const int wrow = (wave >> 1) * 64;    // wave row offset in tile
  const int wcol = (wave & 1) * 32;     // wave col offset in tile
  const int lrow = lane & 15;
  const int koff = (lane >> 4) * 8;     // 0,8,16,24

  const int bm = blockIdx.y * 128;
  const int bn = blockIdx.x * 64;

  // staging: A: thread -> (row tid>>1, 32 halfs at (tid&1)*32)  [coalesced]
  //          B: thread -> (row tid>>2, 16 halfs at (tid&3)*16)  [coalesced]
  const int ar = tid >> 1;
  const int ac = (tid & 1) * 32;
  const int br = tid >> 2;
  const int bc = (tid & 3) * 16;

  const f16* pa = A  + (size_t)(bm + ar) * K + ac;
  const f16* pb = Wt + (size_t)(bn + br) * K + bc;

  f16x8 ra0, ra1, ra2, ra3, rb0, rb1;
  #define LOADG()                                                   \
    ra0 = *reinterpret_cast<const f16x8*>(pa +  0);                 \
    ra1 = *reinterpret_cast<const f16x8*>(pa +  8);                 \
    ra2 = *reinterpret_cast<const f16x8*>(pa + 16);                 \
    ra3 = *reinterpret_cast<const f16x8*>(pa + 24);                 \
    rb0 = *reinterpret_cast<const f16x8*>(pb +  0);                 \
    rb1 = *reinterpret_cast<const f16x8*>(pb +  8);

  f32x4 acc[4][2] = {};

  LOADG();
  for (int k0 = 0; k0 < K; k0 += 64) {
    // commit staged registers to LDS
    *reinterpret_cast<f16x8*>(&As[ar][ac +  0]) = ra0;
    *reinterpret_cast<f16x8*>(&As[ar][ac +  8]) = ra1;
    *reinterpret_cast<f16x8*>(&As[ar][ac + 16]) = ra2;
    *reinterpret_cast<f16x8*>(&As[ar][ac + 24]) = ra3;
    *reinterpret_cast<f16x8*>(&Bs[br][bc +  0]) = rb0;
    *reinterpret_cast<f16x8*>(&Bs[br][bc +  8]) = rb1;
    __syncthreads();

    if (k0 + 64 < K) {            // prefetch next tile (hides HBM under MFMA)
      pa += 64; pb += 64;
      LOADG();
    }

    #pragma unroll
    for (int ks = 0; ks < 2; ++ks) {
      const int kk = ks * 32 + koff;
      const f16x8 a0 = *reinterpret_cast<const f16x8*>(&As[wrow +  0 + lrow][kk]);
      const f16x8 a1 = *reinterpret_cast<const f16x8*>(&As[wrow + 16 + lrow][kk]);
      const f16x8 a2 = *reinterpret_cast<const f16x8*>(&As[wrow + 32 + lrow][kk]);
      const f16x8 a3 = *reinterpret_cast<const f16x8*>(&As[wrow + 48 + lrow][kk]);
      const f16x8 b0 = *reinterpret_cast<const f16x8*>(&Bs[wcol +  0 + lrow][kk]);
      const f16x8 b1 = *reinterpret_cast<const f16x8*>(&Bs[wcol + 16 + lrow][kk]);

      acc[0][0] = __builtin_amdgcn_mfma_f32_16x16x32_f16(a0, b0, acc[0][0], 0, 0, 0);
      acc[0][1] = __builtin_amdgcn_mfma_f32_16x16x32_f16(a0, b1, acc[0][1], 0, 0, 0);
      acc[1][0] = __builtin_amdgcn_mfma_f32_16x16x32_f16(a1, b0, acc[1][0], 0, 0, 0);
      acc[1][1] = __builtin_amdgcn_mfma_f32_16x16x32_f16(a1, b1, acc[1][1], 0, 0, 0);
      acc[2][0] = __builtin_amdgcn_mfma_f32_16x16x32_f16(a2, b0, acc[2][0], 0, 0, 0);
      acc[2][1] = __builtin_amdgcn_mfma_f32_16x16x32_f16(a2, b1, acc[2][1], 0, 0, 0);
      acc[3][0] = __builtin_amdgcn_mfma_f32_16x16x32_f16(a3, b0, acc[3][0], 0, 0, 0);
      acc[3][1] = __builtin_amdgcn_mfma_f32_16x16x32_f16(a3, b1, acc[3][1], 0, 0, 0);
    }
    __syncthreads();
  }
  #undef LOADG

  // epilogue: bias + ReLU + fp16 store (C/D map: col=lane&15, row=(lane>>4)*4+reg)
  const int orow = (lane >> 4) * 4;
  #pragma unroll
  for (int mf = 0; mf < 4; ++mf)
    #pragma unroll
    for (int nf = 0; nf < 2; ++nf) {
      const int col = bn + wcol + nf * 16 + lrow;
      const float bv = BIAS ? bias[col] : 0.f;
      #pragma unroll
      for (int rr = 0; rr < 4; ++rr) {
        const int row = bm + wrow + mf * 16 + orow + rr;
        float v = acc[mf][nf][rr] + bv;
        if (RELU) v = fmaxf(v, 0.f);
        C[(size_t)row * ldc + col] = (f16)v;
      }
    }
}

// ---------------------------------------------------------------------------
// out[b] = h3[b,:256] . mw4 + mb4   (one wave per row; h3 is fp16)
// ---------------------------------------------------------------------------
__global__ __launch_bounds__(256) void k_final(const f16* __restrict__ h3,
                                               const float* __restrict__ mw4,
                                               const float* __restrict__ mb4,
                                               float* __restrict__ out) {
  const int wid = threadIdx.x >> 6;
  const int lane = threadIdx.x & 63;
  const int row = blockIdx.x * 4 + wid;
  const f16* hr = h3 + (size_t)row * 256;
  float s = 0.f;
  #pragma unroll
  for (int d = 0; d < 4; ++d)
    s = fmaf((float)hr[lane + d * 64], mw4[lane + d * 64], s);
  #pragma unroll
  for (int off = 32; off > 0; off >>= 1) s += __shfl_down(s, off);
  if (lane == 0) out[row] = s + mb4[0];
}

// ---------------------------------------------------------------------------
extern "C" void kernel_launch(void* const* d_in, const int* in_sizes, int n_in,
                              void* d_out, int out_size, void* d_ws, size_t ws_size,
                              hipStream_t stream) {
  const float* cand  = (const float*)d_in[0];   // (2048, 512)
  const float* rated = (const float*)d_in[1];   // (4096, 512)
  const float* um    = (const float*)d_in[2];   // (2048, 4096)
  const float* att_w = (const float*)d_in[3];   // (1024, 1)
  // d_in[4] = att_b (cancels in softmax)
  const float* iw1 = (const float*)d_in[5];     // (512, 1024)
  const float* ib1 = (const float*)d_in[6];
  const float* iw2 = (const float*)d_in[7];     // (1024, 512)
  const float* ib2 = (const float*)d_in[8];
  const float* uw1 = (const float*)d_in[9];     // (512, 2048)
  const float* ub1 = (const float*)d_in[10];
  const float* uw2 = (const float*)d_in[11];    // (2048, 1024)
  const float* ub2 = (const float*)d_in[12];
  const float* mw1 = (const float*)d_in[13];    // (1536, 1024)
  const float* mb1 = (const float*)d_in[14];
  const float* mw2 = (const float*)d_in[15];    // (1024, 512)
  const float* mb2 = (const float*)d_in[16];
  const float* mw3 = (const float*)d_in[17];    // (512, 256)
  const float* mb3 = (const float*)d_in[18];
  const float* mw4 = (const float*)d_in[19];    // (256, 1)
  const float* mb4 = (const float*)d_in[20];
  float* out = (float*)d_out;                   // (2048, 1)

  // ---- workspace layout (fp16 element units); ~36 MB total ----
  f16*   hws = (f16*)d_ws;
  float* rs  = (float*)d_ws;            // 4096 fp32 = 8192 half-slots
  size_t off = 8192;
  auto take = [&](size_t n) { f16* p = hws + off; off += n; return p; };
  f16* t_iw1   = take(512 * 1024);
  f16* t_iw2   = take(1024 * 512);
  f16* t_uw1   = take(512 * 2048);
  f16* t_uw2   = take(2048 * 1024);
  f16* t_mw1   = take(1536 * 1024);
  f16* t_mw2   = take(1024 * 512);
  f16* t_mw3   = take(512 * 256);
  f16* t_rated = take(512 * 4096);      // rated^T fp16
  f16* cand_h  = take(2048 * 512);
  f16* uf_h    = take(2048 * 512);
  f16* big     = take(2048 * 2048);     // h_i1 / h_u1 / h_m1 (time-shared)
  f16* Xc      = take(2048 * 1536);     // concat [item_emb | user_emb]
  f16* spare   = take(2048 * 512);
  (void)spare;
  // att_dense (2048x4096 fp16 = 16MB) aliases [big|Xc|spare]: it is dead
  // before G1 writes big and before G2/G4 write Xc.
  f16* att_d = big;
  f16* h_i1 = big;                      // 2048x1024
  f16* h_u1 = big;                      // 2048x2048
  f16* h_m1 = big;                      // 2048x1024
  f16* h_m2 = uf_h;                     // 2048x512  (uf dead after G3)
  f16* h_m3 = cand_h;                   // 2048x256  (cand_h dead after G1)

  dim3 blk(256);

  // 0. attention logits + dense fp16 attention matrix
  k_rs<<<dim3(In / 4), blk, 0, stream>>>(rated, att_w, rs);
  k_att<<<dim3(Bn), blk, 0, stream>>>(um, rs, att_d);

  // 1. weight prep: fp32 [K][N] -> fp16 [N][K]; candidate cast
  k_transpose_f2h<<<dim3( 512/32, 4096/32), blk, 0, stream>>>(rated, t_rated, 4096, 512);
  k_transpose_f2h<<<dim3(1024/32,  512/32), blk, 0, stream>>>(iw1, t_iw1,  512, 1024);
  k_transpose_f2h<<<dim3( 512/32, 1024/32), blk, 0, stream>>>(iw2, t_iw2, 1024,  512);
  k_transpose_f2h<<<dim3(2048/32,  512/32), blk, 0, stream>>>(uw1, t_uw1,  512, 2048);
  k_transpose_f2h<<<dim3(1024/32, 2048/32), blk, 0, stream>>>(uw2, t_uw2, 2048, 1024);
  k_transpose_f2h<<<dim3(1024/32, 1536/32), blk, 0, stream>>>(mw1, t_mw1, 1536, 1024);
  k_transpose_f2h<<<dim3( 512/32, 1024/32), blk, 0, stream>>>(mw2, t_mw2, 1024,  512);
  k_transpose_f2h<<<dim3( 256/32,  512/32), blk, 0, stream>>>(mw3, t_mw3,  512,  256);
  k_cast_f2h<<<dim3(Bn * Dn / 1024), blk, 0, stream>>>(cand, cand_h, Bn * Dn);

  // 2. user_feat = att_dense @ rated   (2048x512x4096 MFMA GEMM, no bias)
  k_hgemm<false, false><<<dim3(512/64, Bn/128), blk, 0, stream>>>(
      att_d, t_rated, nullptr, uf_h, 512, 512, 4096);

  // 3. item MLP (att_d dead from here; big/Xc reusable)
  k_hgemm<true, true><<<dim3(1024/64, Bn/128), blk, 0, stream>>>(cand_h, t_iw1, ib1, h_i1, 1024, 1024, 512);
  k_hgemm<true, true><<<dim3( 512/64, Bn/128), blk, 0, stream>>>(h_i1,   t_iw2, ib2, Xc,   1536,  512, 1024);

  // 4. user MLP (writes second half of concat buffer)
  k_hgemm<true, true><<<dim3(2048/64, Bn/128), blk, 0, stream>>>(uf_h, t_uw1, ub1, h_u1,     2048, 2048, 512);
  k_hgemm<true, true><<<dim3(1024/64, Bn/128), blk, 0, stream>>>(h_u1, t_uw2, ub2, Xc + 512, 1536, 1024, 2048);

  // 5. merge MLP
  k_hgemm<true, true><<<dim3(1024/64, Bn/128), blk, 0, stream>>>(Xc,   t_mw1, mb1, h_m1, 1024, 1024, 1536);
  k_hgemm<true, true><<<dim3( 512/64, Bn/128), blk, 0, stream>>>(h_m1, t_mw2, mb2, h_m2,  512,  512, 1024);
  k_hgemm<true, true><<<dim3( 256/64, Bn/128), blk, 0, stream>>>(h_m2, t_mw3, mb3, h_m3,  256,  256, 512);

  // 6. final projection (fp32 out)
  k_final<<<dim3(Bn / 4), blk, 0, stream>>>(h_m3, mw4, mb4, out);
}

// Round 8
// 290.395 us; speedup vs baseline: 1.1639x; 1.1036x over previous
//
#include <hip/hip_runtime.h>
#include <cstddef>

// Problem constants (fixed by the reference)
constexpr int Bn = 2048;   // batch
constexpr int In = 4096;   // rated items
constexpr int Dn = 512;    // embedding dim

typedef _Float16 f16;
typedef _Float16 f16x8 __attribute__((ext_vector_type(8)));
typedef float    f32x4 __attribute__((ext_vector_type(4)));

// ---------------------------------------------------------------------------
// rs[i] = rated_items[i,:] . att_w[D:2D]  (per-item attention logit).
// cs[b] and att_b are row-constant -> cancel in the row softmax.
// ---------------------------------------------------------------------------
__global__ __launch_bounds__(256) void k_rs(const float* __restrict__ rated,
                                            const float* __restrict__ att_w,
                                            float* __restrict__ rs) {
  const int wid  = threadIdx.x >> 6;
  const int lane = threadIdx.x & 63;
  const int i = blockIdx.x * 4 + wid;
  const float* row = rated + (size_t)i * Dn;
  const float* wr  = att_w + Dn;
  float s = 0.f;
  #pragma unroll
  for (int d = 0; d < Dn / 64; ++d)
    s = fmaf(row[lane + d * 64], wr[lane + d * 64], s);
  #pragma unroll
  for (int off = 32; off > 0; off >>= 1) s += __shfl_down(s, off);
  if (lane == 0) rs[i] = s;
}

// ---------------------------------------------------------------------------
// Dense fp16 attention-weight row:
//   w[b][i] = um!=0 ? exp(rs[i]-m_b)*um[b][i] / S_b : 0,   S_b = SUM exp(rs-m)
// (S is the plain exp-sum over support — round-6 bug was um-weighting it.)
// ---------------------------------------------------------------------------
__global__ __launch_bounds__(256) void k_att(const float* __restrict__ um,
                                             const float* __restrict__ rs,
                                             f16* __restrict__ att) {
  __shared__ float t[In];      // rs-or--inf, then unnormalized weight exp*um
  __shared__ float red[4];
  const int tid = threadIdx.x;
  const int b = blockIdx.x;
  const float* umrow = um + (size_t)b * In;

  float ua[16];
  float lmax = -INFINITY;
  #pragma unroll
  for (int it = 0; it < 4; ++it) {
    const int i = (it * 256 + tid) * 4;
    const float4 v = *reinterpret_cast<const float4*>(umrow + i);
    ua[it * 4 + 0] = v.x; ua[it * 4 + 1] = v.y;
    ua[it * 4 + 2] = v.z; ua[it * 4 + 3] = v.w;
    #pragma unroll
    for (int j = 0; j < 4; ++j) {
      if (ua[it * 4 + j] != 0.f) {
        const float r = rs[i + j];
        t[i + j] = r;
        lmax = fmaxf(lmax, r);
      } else {
        t[i + j] = -INFINITY;
      }
    }
  }
  #pragma unroll
  for (int off = 32; off > 0; off >>= 1) lmax = fmaxf(lmax, __shfl_down(lmax, off));
  if ((tid & 63) == 0) red[tid >> 6] = lmax;
  __syncthreads();
  const float m = fmaxf(fmaxf(red[0], red[1]), fmaxf(red[2], red[3]));
  __syncthreads();   // protect red[] before it is rewritten below

  float lsum = 0.f;
  #pragma unroll
  for (int it = 0; it < 4; ++it) {
    const int i = (it * 256 + tid) * 4;
    #pragma unroll
    for (int j = 0; j < 4; ++j) {
      float v = 0.f;
      if (ua[it * 4 + j] != 0.f) {
        const float e = __expf(t[i + j] - m);
        lsum += e;                    // softmax denominator: plain exp sum
        v = e * ua[it * 4 + j];       // numerator weight: exp * um
      }
      t[i + j] = v;   // own indices only; no race
    }
  }
  #pragma unroll
  for (int off = 32; off > 0; off >>= 1) lsum += __shfl_down(lsum, off);
  if ((tid & 63) == 0) red[tid >> 6] = lsum;
  __syncthreads();   // red visible AND all t[] writes visible
  const float S = red[0] + red[1] + red[2] + red[3];
  const float inv = (S > 0.f) ? 1.0f / S : 0.0f;

  f16* arow = att + (size_t)b * In;
  #pragma unroll
  for (int it = 0; it < 2; ++it) {
    const int i = (it * 256 + tid) * 8;
    f16x8 h;
    #pragma unroll
    for (int j = 0; j < 8; ++j) h[j] = (f16)(t[i + j] * inv);
    *reinterpret_cast<f16x8*>(arow + i) = h;
  }
}

// ---------------------------------------------------------------------------
// Weight prep: src[K][N] fp32 -> dst[N][K] fp16 (transpose), 32x32 LDS tiles.
// ---------------------------------------------------------------------------
__global__ __launch_bounds__(256) void k_transpose_f2h(const float* __restrict__ src,
                                                       f16* __restrict__ dst,
                                                       int K, int N) {
  __shared__ float tile[32][33];
  const int tx = threadIdx.x & 31;
  const int ty = threadIdx.x >> 5;      // 0..7
  const int n0 = blockIdx.x * 32;
  const int k0 = blockIdx.y * 32;
  #pragma unroll
  for (int i = 0; i < 4; ++i)
    tile[ty + i * 8][tx] = src[(size_t)(k0 + ty + i * 8) * N + n0 + tx];
  __syncthreads();
  #pragma unroll
  for (int i = 0; i < 4; ++i)
    dst[(size_t)(n0 + ty + i * 8) * K + k0 + tx] = (f16)tile[tx][ty + i * 8];
}

// Plain fp32 -> fp16 cast (for candidate_items). n multiple of 1024.
__global__ __launch_bounds__(256) void k_cast_f2h(const float* __restrict__ src,
                                                  f16* __restrict__ dst, int n) {
  const int i = (blockIdx.x * 256 + threadIdx.x) * 4;
  if (i < n) {
    const float4 v = *reinterpret_cast<const float4*>(src + i);
    f16 h0 = (f16)v.x, h1 = (f16)v.y, h2 = (f16)v.z, h3 = (f16)v.w;
    f16* p = dst + i;
    p[0] = h0; p[1] = h1; p[2] = h2; p[3] = h3;
  }
}

// ---------------------------------------------------------------------------
// Fused C = act(A @ W + bias), fp16 in / fp32 acc / fp16 out, MFMA.
//   A : MxK row-major fp16, Wt: NxK row-major fp16 (W transposed),
//   C : MxN fp16 with leading dim ldc.
// Tile 64x64, BK=64, 256 threads = 4 waves (2x2); each wave computes a 32x32
// quadrant = 2x2 frags of v_mfma_f32_16x16x32_f16. Register prefetch of the
// next K-tile before the MFMA cluster. LDS 18.4KB -> up to 8 blocks/CU.
// Round-7 profile showed 128x64 tiles gave only 64-256 wgs on 256 CUs
// (Occupancy 5%, MfmaUtil 6%): latency-bound from grid starvation. 64x64
// doubles wg count per layer and allows multi-block co-residency.
// Fragment maps HW-verified (rounds 4 & 7 passed, absmax 3.05e-5).
// ---------------------------------------------------------------------------
template <bool RELU, bool BIAS>
__global__ __launch_bounds__(256) void k_hgemm(const f16* __restrict__ A,
                                               const f16* __restrict__ Wt,
                                               const float* __restrict__ bias,
                                               f16* __restrict__ C, int ldc,
                                               int N, int K) {
  __shared__ __align__(16) f16 As[64][72];   // 64 + 8 pad (rows 144B)
  __shared__ __align__(16) f16 Bs[64][72];

  const int tid  = threadIdx.x;
  const int lane = tid & 63;
  const int wave = tid >> 6;            // 0..3
  const int wrow = (wave >> 1) * 32;    // wave row offset in tile
  const int wcol = (wave & 1) * 32;     // wave col offset in tile
  const int lrow = lane & 15;
  const int koff = (lane >> 4) * 8;     // 0,8,16,24

  const int bm = blockIdx.y * 64;
  const int bn = blockIdx.x * 64;

  // staging: thread -> (row tid>>2, 16-half chunk at (tid&3)*16); x2 f16x8 each
  const int r = tid >> 2;               // 0..63
  const int c = (tid & 3) * 16;         // 0,16,32,48

  const f16* pa = A  + (size_t)(bm + r) * K + c;
  const f16* pb = Wt + (size_t)(bn + r) * K + c;

  f16x8 ra0, ra1, rb0, rb1;
  #define LOADG()                                                   \
    ra0 = *reinterpret_cast<const f16x8*>(pa + 0);                  \
    ra1 = *reinterpret_cast<const f16x8*>(pa + 8);                  \
    rb0 = *reinterpret_cast<const f16x8*>(pb + 0);                  \
    rb1 = *reinterpret_cast<const f16x8*>(pb + 8);

  f32x4 acc[2][2] = {};

  LOADG();
  for (int k0 = 0; k0 < K; k0 += 64) {
    *reinterpret_cast<f16x8*>(&As[r][c + 0]) = ra0;
    *reinterpret_cast<f16x8*>(&As[r][c + 8]) = ra1;
    *reinterpret_cast<f16x8*>(&Bs[r][c + 0]) = rb0;
    *reinterpret_cast<f16x8*>(&Bs[r][c + 8]) = rb1;
    __syncthreads();

    if (k0 + 64 < K) {            // prefetch next tile (hides HBM under MFMA)
      pa += 64; pb += 64;
      LOADG();
    }

    #pragma unroll
    for (int ks = 0; ks < 2; ++ks) {
      const int kk = ks * 32 + koff;
      const f16x8 a0 = *reinterpret_cast<const f16x8*>(&As[wrow +  0 + lrow][kk]);
      const f16x8 a1 = *reinterpret_cast<const f16x8*>(&As[wrow + 16 + lrow][kk]);
      const f16x8 b0 = *reinterpret_cast<const f16x8*>(&Bs[wcol +  0 + lrow][kk]);
      const f16x8 b1 = *reinterpret_cast<const f16x8*>(&Bs[wcol + 16 + lrow][kk]);

      acc[0][0] = __builtin_amdgcn_mfma_f32_16x16x32_f16(a0, b0, acc[0][0], 0, 0, 0);
      acc[0][1] = __builtin_amdgcn_mfma_f32_16x16x32_f16(a0, b1, acc[0][1], 0, 0, 0);
      acc[1][0] = __builtin_amdgcn_mfma_f32_16x16x32_f16(a1, b0, acc[1][0], 0, 0, 0);
      acc[1][1] = __builtin_amdgcn_mfma_f32_16x16x32_f16(a1, b1, acc[1][1], 0, 0, 0);
    }
    __syncthreads();
  }
  #undef LOADG

  // epilogue: bias + ReLU + fp16 store (C/D map: col=lane&15, row=(lane>>4)*4+reg)
  const int orow = (lane >> 4) * 4;
  #pragma unroll
  for (int mf = 0; mf < 2; ++mf)
    #pragma unroll
    for (int nf = 0; nf < 2; ++nf) {
      const int col = bn + wcol + nf * 16 + lrow;
      const float bv = BIAS ? bias[col] : 0.f;
      #pragma unroll
      for (int rr = 0; rr < 4; ++rr) {
        const int row = bm + wrow + mf * 16 + orow + rr;
        float v = acc[mf][nf][rr] + bv;
        if (RELU) v = fmaxf(v, 0.f);
        C[(size_t)row * ldc + col] = (f16)v;
      }
    }
}

// ---------------------------------------------------------------------------
// out[b] = h3[b,:256] . mw4 + mb4   (one wave per row; h3 is fp16)
// ---------------------------------------------------------------------------
__global__ __launch_bounds__(256) void k_final(const f16* __restrict__ h3,
                                               const float* __restrict__ mw4,
                                               const float* __restrict__ mb4,
                                               float* __restrict__ out) {
  const int wid = threadIdx.x >> 6;
  const int lane = threadIdx.x & 63;
  const int row = blockIdx.x * 4 + wid;
  const f16* hr = h3 + (size_t)row * 256;
  float s = 0.f;
  #pragma unroll
  for (int d = 0; d < 4; ++d)
    s = fmaf((float)hr[lane + d * 64], mw4[lane + d * 64], s);
  #pragma unroll
  for (int off = 32; off > 0; off >>= 1) s += __shfl_down(s, off);
  if (lane == 0) out[row] = s + mb4[0];
}

// ---------------------------------------------------------------------------
extern "C" void kernel_launch(void* const* d_in, const int* in_sizes, int n_in,
                              void* d_out, int out_size, void* d_ws, size_t ws_size,
                              hipStream_t stream) {
  const float* cand  = (const float*)d_in[0];   // (2048, 512)
  const float* rated = (const float*)d_in[1];   // (4096, 512)
  const float* um    = (const float*)d_in[2];   // (2048, 4096)
  const float* att_w = (const float*)d_in[3];   // (1024, 1)
  // d_in[4] = att_b (cancels in softmax)
  const float* iw1 = (const float*)d_in[5];     // (512, 1024)
  const float* ib1 = (const float*)d_in[6];
  const float* iw2 = (const float*)d_in[7];     // (1024, 512)
  const float* ib2 = (const float*)d_in[8];
  const float* uw1 = (const float*)d_in[9];     // (512, 2048)
  const float* ub1 = (const float*)d_in[10];
  const float* uw2 = (const float*)d_in[11];    // (2048, 1024)
  const float* ub2 = (const float*)d_in[12];
  const float* mw1 = (const float*)d_in[13];    // (1536, 1024)
  const float* mb1 = (const float*)d_in[14];
  const float* mw2 = (const float*)d_in[15];    // (1024, 512)
  const float* mb2 = (const float*)d_in[16];
  const float* mw3 = (const float*)d_in[17];    // (512, 256)
  const float* mb3 = (const float*)d_in[18];
  const float* mw4 = (const float*)d_in[19];    // (256, 1)
  const float* mb4 = (const float*)d_in[20];
  float* out = (float*)d_out;                   // (2048, 1)

  // ---- workspace layout (fp16 element units); ~36 MB total ----
  f16*   hws = (f16*)d_ws;
  float* rs  = (float*)d_ws;            // 4096 fp32 = 8192 half-slots
  size_t off = 8192;
  auto take = [&](size_t n) { f16* p = hws + off; off += n; return p; };
  f16* t_iw1   = take(512 * 1024);
  f16* t_iw2   = take(1024 * 512);
  f16* t_uw1   = take(512 * 2048);
  f16* t_uw2   = take(2048 * 1024);
  f16* t_mw1   = take(1536 * 1024);
  f16* t_mw2   = take(1024 * 512);
  f16* t_mw3   = take(512 * 256);
  f16* t_rated = take(512 * 4096);      // rated^T fp16
  f16* cand_h  = take(2048 * 512);
  f16* uf_h    = take(2048 * 512);
  f16* big     = take(2048 * 2048);     // h_i1 / h_u1 / h_m1 (time-shared)
  f16* Xc      = take(2048 * 1536);     // concat [item_emb | user_emb]
  f16* spare   = take(2048 * 512);
  (void)spare;
  // att_dense (2048x4096 fp16 = 16MB) aliases contiguous [big|Xc|spare]:
  // dead before G1 writes big and before G2/G4 write Xc.
  f16* att_d = big;
  f16* h_i1 = big;                      // 2048x1024
  f16* h_u1 = big;                      // 2048x2048
  f16* h_m1 = big;                      // 2048x1024
  f16* h_m2 = uf_h;                     // 2048x512  (uf dead after G3)
  f16* h_m3 = cand_h;                   // 2048x256  (cand_h dead after G1)

  dim3 blk(256);

  // 0. attention logits + dense fp16 attention matrix
  k_rs<<<dim3(In / 4), blk, 0, stream>>>(rated, att_w, rs);
  k_att<<<dim3(Bn), blk, 0, stream>>>(um, rs, att_d);

  // 1. weight prep: fp32 [K][N] -> fp16 [N][K]; candidate cast
  k_transpose_f2h<<<dim3( 512/32, 4096/32), blk, 0, stream>>>(rated, t_rated, 4096, 512);
  k_transpose_f2h<<<dim3(1024/32,  512/32), blk, 0, stream>>>(iw1, t_iw1,  512, 1024);
  k_transpose_f2h<<<dim3( 512/32, 1024/32), blk, 0, stream>>>(iw2, t_iw2, 1024,  512);
  k_transpose_f2h<<<dim3(2048/32,  512/32), blk, 0, stream>>>(uw1, t_uw1,  512, 2048);
  k_transpose_f2h<<<dim3(1024/32, 2048/32), blk, 0, stream>>>(uw2, t_uw2, 2048, 1024);
  k_transpose_f2h<<<dim3(1024/32, 1536/32), blk, 0, stream>>>(mw1, t_mw1, 1536, 1024);
  k_transpose_f2h<<<dim3( 512/32, 1024/32), blk, 0, stream>>>(mw2, t_mw2, 1024,  512);
  k_transpose_f2h<<<dim3( 256/32,  512/32), blk, 0, stream>>>(mw3, t_mw3,  512,  256);
  k_cast_f2h<<<dim3(Bn * Dn / 1024), blk, 0, stream>>>(cand, cand_h, Bn * Dn);

  // 2. user_feat = att_dense @ rated   (2048x512x4096 MFMA GEMM, no bias)
  k_hgemm<false, false><<<dim3(512/64, Bn/64), blk, 0, stream>>>(
      att_d, t_rated, nullptr, uf_h, 512, 512, 4096);

  // 3. item MLP (att_d dead from here; big/Xc reusable)
  k_hgemm<true, true><<<dim3(1024/64, Bn/64), blk, 0, stream>>>(cand_h, t_iw1, ib1, h_i1, 1024, 1024, 512);
  k_hgemm<true, true><<<dim3( 512/64, Bn/64), blk, 0, stream>>>(h_i1,   t_iw2, ib2, Xc,   1536,  512, 1024);

  // 4. user MLP (writes second half of concat buffer)
  k_hgemm<true, true><<<dim3(2048/64, Bn/64), blk, 0, stream>>>(uf_h, t_uw1, ub1, h_u1,     2048, 2048, 512);
  k_hgemm<true, true><<<dim3(1024/64, Bn/64), blk, 0, stream>>>(h_u1, t_uw2, ub2, Xc + 512, 1536, 1024, 2048);

  // 5. merge MLP
  k_hgemm<true, true><<<dim3(1024/64, Bn/64), blk, 0, stream>>>(Xc,   t_mw1, mb1, h_m1, 1024, 1024, 1536);
  k_hgemm<true, true><<<dim3( 512/64, Bn/64), blk, 0, stream>>>(h_m1, t_mw2, mb2, h_m2,  512,  512, 1024);
  k_hgemm<true, true><<<dim3( 256/64, Bn/64), blk, 0, stream>>>(h_m2, t_mw3, mb3, h_m3,  256,  256, 512);

  // 6. final projection (fp32 out)
  k_final<<<dim3(Bn / 4), blk, 0, stream>>>(h_m3, mw4, mb4, out);
}